// Round 11
// baseline (255.441 us; speedup 1.0000x reference)
//
#include <hip/hip_runtime.h>
#include <hip/hip_bf16.h>

#define HIDC 64
#define NEG_SLOPE 0.2f
#define SCAN_G 128     // blocks in the two-phase scan

typedef __hip_bfloat16 bf16;
typedef short bf16x8 __attribute__((ext_vector_type(8)));
typedef float floatx4 __attribute__((ext_vector_type(4)));
typedef int intx4 __attribute__((ext_vector_type(4)));

static __device__ __forceinline__ float b2f(bf16 v) { return __bfloat162float(v); }

static __device__ __forceinline__ unsigned short f2us(float f) {
  bf16 b = __float2bfloat16(f);
  union { bf16 b; unsigned short u; } c;
  c.b = b;
  return c.u;
}

// dtype-specialized loads
template <bool FF>
static __device__ __forceinline__ float ld(const void* __restrict__ p, size_t i) {
  return FF ? ((const float*)p)[i] : b2f(((const bf16*)p)[i]);
}
static __device__ __forceinline__ float ldr(const void* __restrict__ p, size_t i,
                                            bool ff) {
  return ff ? ((const float*)p)[i] : b2f(((const bf16*)p)[i]);
}
template <bool I64>
static __device__ __forceinline__ int ldi(const int* __restrict__ p, long long i) {
  return I64 ? (int)((const long long*)p)[i] : p[i];
}
static __device__ __forceinline__ int clampN(int v, int N) {
  return ((unsigned)v < (unsigned)N) ? v : 0;
}

// nontemporal 16B load (slots are read exactly once in k_agg)
static __device__ __forceinline__ int4 ntload4(const int4* __restrict__ p) {
  intx4 v = __builtin_nontemporal_load((const intx4*)p);
  return make_int4(v.x, v.y, v.z, v.w);
}

// Per-wave local dtype detection (1 load + ballot; uniform across waves since
// every wave samples the same 32 words).
static __device__ __forceinline__ bool det_f32(const unsigned* __restrict__ hw) {
  unsigned w = hw[threadIdx.x & 31];
  int ex = (w >> 7) & 0xFF;
  unsigned long long b = __ballot(ex >= 99 && ex <= 135);
  return __popcll(b) < 32;  // true => fp32 inputs
}
static __device__ __forceinline__ bool det_i64(const int* __restrict__ ei) {
  int v = ei[2 * (threadIdx.x & 31) + 1];
  return __ballot(v != 0) == 0ULL;  // true => int64 layout
}

// ---------------- MFMA x-GEMM + logits + in-degree histogram ----------------
// Round 11 = round-10 pipeline (239.9us verified best) with k_agg split into
// THREE range dispatches (~24us each) as a MEASUREMENT: with ~8 bench
// iterations the top-5 only ever shows the slowest kernel x5, so k_xh/k_es/
// k_bscan (~163us combined, individually <72us) have no counter rows. The
// split lowers the visibility cutoff to ~25us and surfaces the slowest of
// them with full counters. Boundary cost ~1us/dispatch (round-8 measurement).
template <bool FF, bool I64>
static __device__ __forceinline__ void xh_body(
    const void* __restrict__ h, const void* __restrict__ W,
    const void* __restrict__ att_src, const void* __restrict__ att_dst,
    const int* __restrict__ ei, bf16* __restrict__ x,
    float* __restrict__ a_src, float* __restrict__ a_dst,
    int* __restrict__ cnt, int* __restrict__ erank, int N, int E,
    unsigned short* __restrict__ hls, unsigned short* __restrict__ wls) {
  // histogram + rank capture (grid-stride; padded counters, 1 per 64B line)
  for (long long e = (long long)blockIdx.x * 256 + threadIdx.x; e < E;
       e += (long long)gridDim.x * 256) {
    int dst = clampN(ldi<I64>(ei, (long long)E + e), N);
    erank[e] = atomicAdd(&cnt[(size_t)dst * 16], 1);
  }
  const int t = threadIdx.x;
  const long long n0 = (long long)blockIdx.x * 64;
  {  // stage W^T: thread t = global col c; LDS row permuted within head
    const int c = t;
    const int jn = c & 63, hd = c >> 6;
    const int r = hd * 64 + (jn & 3) * 16 + (jn >> 2);
#pragma unroll
    for (int q = 0; q < 8; q++) {
      unsigned short u[8];
#pragma unroll
      for (int j = 0; j < 8; j++) {
        int k = q * 8 + j;
        u[j] = FF ? f2us(((const float*)W)[(size_t)k * 256 + c])
                  : ((const unsigned short*)W)[(size_t)k * 256 + c];
      }
      int4 v = make_int4((int)(u[0] | ((unsigned)u[1] << 16)),
                         (int)(u[2] | ((unsigned)u[3] << 16)),
                         (int)(u[4] | ((unsigned)u[5] << 16)),
                         (int)(u[6] | ((unsigned)u[7] << 16)));
      *(int4*)&wls[r * 64 + (q ^ (r & 7)) * 8] = v;
    }
  }
  {  // stage h tile: 64 rows x 8 chunks; thread -> (row=t>>2, 2 chunks)
    const int row = t >> 2;
    const long long n = n0 + row;
#pragma unroll
    for (int dq = 0; dq < 2; dq++) {
      int q = (t & 3) * 2 + dq;
      int4 v;
      if (n < N) {
        if (FF) {
          const float4* hp = (const float4*)h + n * 16 + q * 2;
          float4 f0 = hp[0], f1 = hp[1];
          v = make_int4((int)(f2us(f0.x) | ((unsigned)f2us(f0.y) << 16)),
                        (int)(f2us(f0.z) | ((unsigned)f2us(f0.w) << 16)),
                        (int)(f2us(f1.x) | ((unsigned)f2us(f1.y) << 16)),
                        (int)(f2us(f1.z) | ((unsigned)f2us(f1.w) << 16)));
        } else {
          v = *((const int4*)((const unsigned short*)h + n * 64 + q * 8));
        }
      } else {
        v = make_int4(0, 0, 0, 0);
      }
      *(int4*)&hls[row * 64 + (q ^ (row & 7)) * 8] = v;
    }
  }
  __syncthreads();
  const int w = t >> 6;          // wave = head = col group of 64
  const int lane = t & 63;
  const int lm = lane & 15, lq = lane >> 4;
  bf16x8 af[4][2];
#pragma unroll
  for (int nt = 0; nt < 4; nt++)
#pragma unroll
    for (int ks = 0; ks < 2; ks++) {
      int m = nt * 16 + lm;
      int q = ks * 4 + lq;
      af[nt][ks] = *(const bf16x8*)&hls[m * 64 + (q ^ (m & 7)) * 8];
    }
  floatx4 acc[4][4];
#pragma unroll
  for (int nt = 0; nt < 4; nt++)
#pragma unroll
    for (int ct = 0; ct < 4; ct++) acc[nt][ct] = (floatx4){0.f, 0.f, 0.f, 0.f};
#pragma unroll
  for (int ct = 0; ct < 4; ct++) {
    int c = w * 64 + ct * 16 + lm;   // LDS row (global col w*64 + 4*lm + ct)
    bf16x8 b0 = *(const bf16x8*)&wls[c * 64 + ((lq) ^ (c & 7)) * 8];
    bf16x8 b1 = *(const bf16x8*)&wls[c * 64 + ((4 + lq) ^ (c & 7)) * 8];
#pragma unroll
    for (int nt = 0; nt < 4; nt++) {
      acc[nt][ct] = __builtin_amdgcn_mfma_f32_16x16x32_bf16(af[nt][0], b0,
                                                            acc[nt][ct], 0, 0, 0);
      acc[nt][ct] = __builtin_amdgcn_mfma_f32_16x16x32_bf16(af[nt][1], b1,
                                                            acc[nt][ct], 0, 0, 0);
    }
  }
  // epilogue: vectorized x store + per-head logits via 16-lane shfl_xor
  float as_c[4], ad_c[4];
#pragma unroll
  for (int ct = 0; ct < 4; ct++) {
    as_c[ct] = ld<FF>(att_src, w * 64 + lm * 4 + ct);
    ad_c[ct] = ld<FF>(att_dst, w * 64 + lm * 4 + ct);
  }
#pragma unroll
  for (int nt = 0; nt < 4; nt++) {
    float ps[4] = {0.f, 0.f, 0.f, 0.f}, pd[4] = {0.f, 0.f, 0.f, 0.f};
#pragma unroll
    for (int ct = 0; ct < 4; ct++) {
#pragma unroll
      for (int r = 0; r < 4; r++) {
        ps[r] += acc[nt][ct][r] * as_c[ct];
        pd[r] += acc[nt][ct][r] * ad_c[ct];
      }
    }
    long long nb = n0 + nt * 16 + lq * 4;
#pragma unroll
    for (int r = 0; r < 4; r++) {
      long long n = nb + r;
      if (n < N) {
        ushort4 us = make_ushort4(f2us(acc[nt][0][r]), f2us(acc[nt][1][r]),
                                  f2us(acc[nt][2][r]), f2us(acc[nt][3][r]));
        *(ushort4*)&x[n * 256 + w * 64 + lm * 4] = us;
      }
    }
#pragma unroll
    for (int mask = 1; mask < 16; mask <<= 1) {
#pragma unroll
      for (int r = 0; r < 4; r++) {
        ps[r] += __shfl_xor(ps[r], mask);
        pd[r] += __shfl_xor(pd[r], mask);
      }
    }
    if (lm == 0) {
#pragma unroll
      for (int r = 0; r < 4; r++) {
        long long n = nb + r;
        if (n < N) {
          a_src[n * 4 + w] = ps[r];
          a_dst[n * 4 + w] = pd[r];
        }
      }
    }
  }
}

__global__ void __launch_bounds__(256) k_xh(
    const void* __restrict__ h, const void* __restrict__ W,
    const void* __restrict__ att_src, const void* __restrict__ att_dst,
    const int* __restrict__ ei, bf16* __restrict__ x,
    float* __restrict__ a_src, float* __restrict__ a_dst,
    int* __restrict__ cnt, int* __restrict__ erank, int N, int E) {
  __shared__ alignas(16) unsigned short hls[64 * 64];    // 8 KB (shared by all
  __shared__ alignas(16) unsigned short wls[256 * 64];   // 32 KB  instantiations)
  bool f32 = det_f32((const unsigned*)h);
  bool i64 = det_i64(ei);
  if (f32) {
    if (i64) xh_body<true, true>(h, W, att_src, att_dst, ei, x, a_src, a_dst, cnt, erank, N, E, hls, wls);
    else     xh_body<true, false>(h, W, att_src, att_dst, ei, x, a_src, a_dst, cnt, erank, N, E, hls, wls);
  } else {
    if (i64) xh_body<false, true>(h, W, att_src, att_dst, ei, x, a_src, a_dst, cnt, erank, N, E, hls, wls);
    else     xh_body<false, false>(h, W, att_src, att_dst, ei, x, a_src, a_dst, cnt, erank, N, E, hls, wls);
  }
}

// ------------- scan: per-chunk local prefix + last-block bsum scan ----------
// Reads the PADDED cnt (one counter per 64B line) with plain loads — coherent
// across the kernel boundary. offs[] keeps the CHUNK-LOCAL exclusive prefix,
// bbase[] the per-chunk base; consumers add bbase[n / C].
__global__ void __launch_bounds__(1024) k_bscan(
    const void* __restrict__ W_edge, const void* __restrict__ att_edge,
    const unsigned* __restrict__ hw, const int* __restrict__ cnt,
    int* __restrict__ offs, int* __restrict__ bsum, int* __restrict__ bbase,
    int* __restrict__ done, float* __restrict__ M, int N) {
  int b = blockIdx.x, t = threadIdx.x;
  if (b == 0 && t < 768) {
    bool ff = det_f32(hw);
    int wv = t >> 6, lane = t & 63;
    int d = wv >> 2, hh = wv & 3;
    float p = ldr(W_edge, (size_t)d * 256 + hh * 64 + lane, ff) *
              ldr(att_edge, (size_t)hh * 64 + lane, ff);
#pragma unroll
    for (int o = 32; o; o >>= 1) p += __shfl_down(p, o);
    if (lane == 0) M[d * 4 + hh] = p;
  }
  const int C = (N + SCAN_G - 1) / SCAN_G;
  const int b0 = b * C;
  __shared__ int ts[1024];
  __shared__ int lastf;
  int v = 0;
  if (t < C && b0 + t < N) v = cnt[(size_t)(b0 + t) * 16];
  ts[t] = v;
  __syncthreads();
  for (int off = 1; off < 1024; off <<= 1) {
    int u = (t >= off) ? ts[t - off] : 0;
    __syncthreads();
    ts[t] += u;
    __syncthreads();
  }
  if (t < C && b0 + t < N) offs[b0 + t] = ts[t] - v;  // chunk-local exclusive
  if (t == 1023) {
    atomicExch(&bsum[b], ts[1023]);   // device-scope visible chunk total
    __threadfence();
    int old = atomicAdd(done, 1);
    lastf = (old == SCAN_G - 1) ? 1 : 0;
  }
  __syncthreads();
  if (lastf) {  // this block saw all other totals published
    int w = (t < SCAN_G) ? atomicAdd(&bsum[t], 0) : 0;  // atomic read
    ts[t] = w;
    __syncthreads();
    for (int off = 1; off < 1024; off <<= 1) {
      int u = (t >= off) ? ts[t - off] : 0;
      __syncthreads();
      ts[t] += u;
      __syncthreads();
    }
    if (t < SCAN_G) bbase[t] = ts[t] - w;  // exclusive block base
  }
}

// ---------------- fused edge weights + CSR scatter (one 16B slot) ------------
// Atomic-free: pos = offs_local[dst] + bbase[dst/C] + erank[e]. Slot store is
// a PLAIN int4 (through L2; ntstore quadrupled WRITE_SIZE, round-6 counters).
template <bool FF, bool I64>
static __device__ __forceinline__ void es_body(
    const int* __restrict__ ei, const void* __restrict__ eattr,
    const float* __restrict__ a_src, const float* __restrict__ a_dst,
    const float* __restrict__ M, const int* __restrict__ offs,
    const int* __restrict__ bbase, const int* __restrict__ erank,
    int4* __restrict__ slots, int E, int N, int C,
    unsigned* __restrict__ sattr) {
  const long long e0 = (long long)blockIdx.x * 256;
  {  // stage this block's eattr strip: 6B/edge (bf16) or 12B/edge (f32)
    const unsigned bpe = FF ? 12u : 6u;
    const unsigned* gsrc = (const unsigned*)((const char*)eattr + e0 * bpe);
    unsigned ndw = FF ? 768u : 384u;
    long long bytes_left = ((long long)E - e0) * bpe;
    if (bytes_left < 0) bytes_left = 0;
    unsigned max_dw = (unsigned)((bytes_left + 3) >> 2);
    if (ndw > max_dw) ndw = max_dw;
    for (unsigned i = threadIdx.x; i < ndw; i += 256) sattr[i] = gsrc[i];
  }
  __syncthreads();
  long long e = e0 + threadIdx.x;
  if (e >= E) return;
  int src = clampN(ldi<I64>(ei, e), N);
  int dst = clampN(ldi<I64>(ei, (long long)E + e), N);
  int pos = offs[dst] + bbase[dst / C] + erank[e];
  float ea0, ea1, ea2;
  if (FF) {
    const float* sf = (const float*)sattr;
    ea0 = sf[threadIdx.x * 3 + 0];
    ea1 = sf[threadIdx.x * 3 + 1];
    ea2 = sf[threadIdx.x * 3 + 2];
  } else {
    const unsigned short* su = (const unsigned short*)sattr;
    ea0 = __uint_as_float((unsigned)su[threadIdx.x * 3 + 0] << 16);
    ea1 = __uint_as_float((unsigned)su[threadIdx.x * 3 + 1] << 16);
    ea2 = __uint_as_float((unsigned)su[threadIdx.x * 3 + 2] << 16);
  }
  const float4 m0 = ((const float4*)M)[0];
  const float4 m1 = ((const float4*)M)[1];
  const float4 m2 = ((const float4*)M)[2];
  const float4 as4 = ((const float4*)a_src)[src];
  const float4 ad4 = ((const float4*)a_dst)[dst];
  float al[4];
  al[0] = as4.x + ad4.x + ea0 * m0.x + ea1 * m1.x + ea2 * m2.x;
  al[1] = as4.y + ad4.y + ea0 * m0.y + ea1 * m1.y + ea2 * m2.y;
  al[2] = as4.z + ad4.z + ea0 * m0.z + ea1 * m1.z + ea2 * m2.z;
  al[3] = as4.w + ad4.w + ea0 * m0.w + ea1 * m1.w + ea2 * m2.w;
  unsigned short u[4];
#pragma unroll
  for (int hh = 0; hh < 4; hh++) {
    float a = al[hh];
    a = (a > 0.f) ? a : NEG_SLOPE * a;
    a = fminf(fmaxf(a, -60.f), 60.f);
    u[hh] = f2us(__expf(a));
  }
  slots[pos] = make_int4(src, (int)(u[0] | ((unsigned)u[1] << 16)),
                         (int)(u[2] | ((unsigned)u[3] << 16)), 0);
}

__global__ void __launch_bounds__(256) k_es(
    const int* __restrict__ ei, const void* __restrict__ eattr,
    const float* __restrict__ a_src, const float* __restrict__ a_dst,
    const float* __restrict__ M, const unsigned* __restrict__ hw,
    const int* __restrict__ offs, const int* __restrict__ bbase,
    const int* __restrict__ erank, int4* __restrict__ slots, int E, int N,
    int C) {
  __shared__ unsigned sattr[768];
  bool f32 = det_f32(hw);
  bool i64 = det_i64(ei);
  if (f32) {
    if (i64) es_body<true, true>(ei, eattr, a_src, a_dst, M, offs, bbase, erank, slots, E, N, C, sattr);
    else     es_body<true, false>(ei, eattr, a_src, a_dst, M, offs, bbase, erank, slots, E, N, C, sattr);
  } else {
    if (i64) es_body<false, true>(ei, eattr, a_src, a_dst, M, offs, bbase, erank, slots, E, N, C, sattr);
    else     es_body<false, false>(ei, eattr, a_src, a_dst, M, offs, bbase, erank, slots, E, N, C, sattr);
  }
}

// ---------------- aggregation + head-mean + LayerNorm + SiLU -----------------
// Round-3 winner body (one wave/node, uint2/lane, scalar slot base via
// readfirstlane, 8-deep MLP, nt slot loads) with a [rn0,rn1) node range so
// the launcher can split it 3 ways (measurement; see k_xh comment).
static __device__ __forceinline__ uint2 xgat(const uint2* __restrict__ xr,
                                             int src, int lane) {
  int ss = __builtin_amdgcn_readfirstlane(src);
  return xr[(size_t)(unsigned)ss * 64 + lane];
}

__global__ void __launch_bounds__(256) k_agg(
    const int* __restrict__ offs, const int* __restrict__ bbase,
    const int4* __restrict__ slots, const unsigned* __restrict__ xu,
    const unsigned* __restrict__ hw, const void* __restrict__ bias,
    const void* __restrict__ gamma, const void* __restrict__ beta,
    void* __restrict__ out, int N, int E, int C, int rn0, int rn1) {
  const int t = threadIdx.x;
  const int wv = t >> 6, lane = t & 63;
  const int n = rn0 + blockIdx.x * 4 + wv;
  if (n >= rn1) return;
  const int head2 = lane >> 5;                       // which packed word (q.y/q.z)
  const unsigned wshift = (lane & 16) ? 0u : 16u;    // even head -> lo16
  const uint2* __restrict__ xr = (const uint2*)xu;   // [N][64] uint2 rows

  int s0 = __builtin_amdgcn_readfirstlane(offs[n] + bbase[n / C]);
  int s1 = (n + 1 < N)
               ? __builtin_amdgcn_readfirstlane(offs[n + 1] + bbase[(n + 1) / C])
               : E;

  float a0 = 0.f, a1 = 0.f, a2 = 0.f, a3 = 0.f, ws = 0.f;

#define ACC4(q, d)                                                    \
  do {                                                                \
    unsigned ee = head2 ? (unsigned)(q).z : (unsigned)(q).y;          \
    float wv_ = __uint_as_float((ee << wshift) & 0xffff0000u);        \
    a0 += wv_ * __uint_as_float((d).x << 16);                         \
    a1 += wv_ * __uint_as_float((d).x & 0xffff0000u);                 \
    a2 += wv_ * __uint_as_float((d).y << 16);                         \
    a3 += wv_ * __uint_as_float((d).y & 0xffff0000u);                 \
    ws += wv_;                                                        \
  } while (0)

  int i = s0;
  for (; i + 8 <= s1; i += 8) {   // 8 slot loads, then 8 gathers in flight
    int4 q0 = ntload4(&slots[i + 0]);
    int4 q1 = ntload4(&slots[i + 1]);
    int4 q2 = ntload4(&slots[i + 2]);
    int4 q3 = ntload4(&slots[i + 3]);
    int4 q4 = ntload4(&slots[i + 4]);
    int4 q5 = ntload4(&slots[i + 5]);
    int4 q6 = ntload4(&slots[i + 6]);
    int4 q7 = ntload4(&slots[i + 7]);
    uint2 d0 = xgat(xr, q0.x, lane);
    uint2 d1 = xgat(xr, q1.x, lane);
    uint2 d2 = xgat(xr, q2.x, lane);
    uint2 d3 = xgat(xr, q3.x, lane);
    uint2 d4 = xgat(xr, q4.x, lane);
    uint2 d5 = xgat(xr, q5.x, lane);
    uint2 d6 = xgat(xr, q6.x, lane);
    uint2 d7 = xgat(xr, q7.x, lane);
    ACC4(q0, d0); ACC4(q1, d1); ACC4(q2, d2); ACC4(q3, d3);
    ACC4(q4, d4); ACC4(q5, d5); ACC4(q6, d6); ACC4(q7, d7);
  }
  for (; i + 4 <= s1; i += 4) {
    int4 q0 = ntload4(&slots[i + 0]);
    int4 q1 = ntload4(&slots[i + 1]);
    int4 q2 = ntload4(&slots[i + 2]);
    int4 q3 = ntload4(&slots[i + 3]);
    uint2 d0 = xgat(xr, q0.x, lane);
    uint2 d1 = xgat(xr, q1.x, lane);
    uint2 d2 = xgat(xr, q2.x, lane);
    uint2 d3 = xgat(xr, q3.x, lane);
    ACC4(q0, d0); ACC4(q1, d1); ACC4(q2, d2); ACC4(q3, d3);
  }
  for (; i < s1; i++) {
    int4 q = ntload4(&slots[i]);
    uint2 d = xgat(xr, q.x, lane);
    ACC4(q, d);
  }
#undef ACC4

  // per-head softmax normalization, then mean over the 4 heads (xor 16,32)
  float inv = 1.f / (ws + 1e-16f);
  float v0 = a0 * inv, v1 = a1 * inv, v2 = a2 * inv, v3 = a3 * inv;
  v0 += __shfl_xor(v0, 16); v1 += __shfl_xor(v1, 16);
  v2 += __shfl_xor(v2, 16); v3 += __shfl_xor(v3, 16);
  v0 += __shfl_xor(v0, 32); v1 += __shfl_xor(v1, 32);
  v2 += __shfl_xor(v2, 32); v3 += __shfl_xor(v3, 32);

  bool ff = det_f32(hw);
  const int c0 = (lane & 15) * 4;
  float m0 = v0 * 0.25f + ldr(bias, c0 + 0, ff);
  float m1 = v1 * 0.25f + ldr(bias, c0 + 1, ff);
  float m2 = v2 * 0.25f + ldr(bias, c0 + 2, ff);
  float m3 = v3 * 0.25f + ldr(bias, c0 + 3, ff);

  // LayerNorm over 64 channels: reduce within the 16-lane quad group
  float s = (m0 + m1) + (m2 + m3);
  s += __shfl_xor(s, 1); s += __shfl_xor(s, 2);
  s += __shfl_xor(s, 4); s += __shfl_xor(s, 8);
  float mu = s * 0.015625f;
  float d0 = m0 - mu, d1 = m1 - mu, d2 = m2 - mu, d3 = m3 - mu;
  float vq = (d0 * d0 + d1 * d1) + (d2 * d2 + d3 * d3);
  vq += __shfl_xor(vq, 1); vq += __shfl_xor(vq, 2);
  vq += __shfl_xor(vq, 4); vq += __shfl_xor(vq, 8);
  float rstd = rsqrtf(vq * 0.015625f + 1e-5f);

  if ((lane >> 4) == 0) {  // one 16-lane group writes the node's 64 channels
    float y0 = d0 * rstd * ldr(gamma, c0 + 0, ff) + ldr(beta, c0 + 0, ff);
    float y1 = d1 * rstd * ldr(gamma, c0 + 1, ff) + ldr(beta, c0 + 1, ff);
    float y2 = d2 * rstd * ldr(gamma, c0 + 2, ff) + ldr(beta, c0 + 2, ff);
    float y3 = d3 * rstd * ldr(gamma, c0 + 3, ff) + ldr(beta, c0 + 3, ff);
    float r0 = y0 / (1.f + __expf(-y0));
    float r1 = y1 / (1.f + __expf(-y1));
    float r2 = y2 / (1.f + __expf(-y2));
    float r3 = y3 / (1.f + __expf(-y3));
    size_t ob = (size_t)n * 64 + c0;
    if (ff) {
      *(float4*)((float*)out + ob) = make_float4(r0, r1, r2, r3);
    } else {
      *(ushort4*)((bf16*)out + ob) =
          make_ushort4(f2us(r0), f2us(r1), f2us(r2), f2us(r3));
    }
  }
}

extern "C" void kernel_launch(void* const* d_in, const int* in_sizes, int n_in,
                              void* d_out, int out_size, void* d_ws,
                              size_t ws_size, hipStream_t stream) {
  const void* h        = d_in[1];
  const int*  ei       = (const int*)d_in[2];
  const void* eattr    = d_in[3];
  const void* W        = d_in[4];
  const void* att_src  = d_in[5];
  const void* att_dst  = d_in[6];
  const void* W_edge   = d_in[7];
  const void* att_edge = d_in[8];
  const void* bias     = d_in[9];
  const void* gamma    = d_in[10];
  const void* beta     = d_in[11];

  const int N = in_sizes[1] / HIDC;       // h has N*64 elements (any dtype)
  const int E = in_sizes[3] / 3;          // edge_attr has E*3 elements
  const int C = (N + SCAN_G - 1) / SCAN_G;

  // Workspace layout (~47 MB), 16B-aligned segments.
  char* p = (char*)d_ws;
  float* M    = (float*)p; p += 64;                      // 12 floats
  bf16* x     = (bf16*)p;  p += (size_t)N * 256 * 2;     // 25.6 MB
  float* asrc = (float*)p; p += (size_t)N * 4 * 4;       // 0.8 MB
  float* adst = (float*)p; p += (size_t)N * 4 * 4;       // 0.8 MB
  int4* slots = (int4*)p;  p += (size_t)E * 16;          // 12.8 MB
  int* cnt    = (int*)p;   p += (size_t)N * 64;          // 3.2 MB, 1 ctr/64B line
  int* done   = (int*)p;   p += 64;                      // zeroed (with cnt)
  int* offs   = (int*)p;   p += ((size_t)N + 4) * 4;
  int* erank  = (int*)p;   p += (size_t)E * 4;           // 3.2 MB
  int* bsum   = (int*)p;   p += SCAN_G * 4;
  int* bbase  = (int*)p;   p += SCAN_G * 4;

  size_t need = (size_t)(p - (char*)d_ws);
  if (ws_size < need || N <= 0 || E <= 0) {
    hipMemsetAsync(d_out, 0, (size_t)out_size * 2, stream);
    return;
  }

  hipMemsetAsync(cnt, 0, (size_t)N * 64 + 64, stream);  // cnt + done

  k_xh<<<(N + 63) / 64, 256, 0, stream>>>(h, W, att_src, att_dst, ei, x,
                                          asrc, adst, cnt, erank, N, E);
  k_bscan<<<SCAN_G, 1024, 0, stream>>>(W_edge, att_edge, (const unsigned*)h,
                                       cnt, offs, bsum, bbase, done, M, N);
  k_es<<<(E + 255) / 256, 256, 0, stream>>>(ei, eattr, asrc, adst, M,
                                            (const unsigned*)h, offs, bbase,
                                            erank, slots, E, N, C);
  // k_agg split 3-way (measurement round: lowers top-5 visibility cutoff to
  // ~25us so the slowest of k_xh/k_es/k_bscan surfaces with counters).
  int r1 = ((N / 3) + 3) & ~3;
  int r2 = ((2 * N / 3) + 3) & ~3;
  if (r1 > N) r1 = N;
  if (r2 > N) r2 = N;
  if (r1 > 0)
    k_agg<<<(r1 + 3) / 4, 256, 0, stream>>>(offs, bbase, slots,
                                            (const unsigned*)x,
                                            (const unsigned*)h, bias, gamma,
                                            beta, d_out, N, E, C, 0, r1);
  if (r2 > r1)
    k_agg<<<(r2 - r1 + 3) / 4, 256, 0, stream>>>(offs, bbase, slots,
                                                 (const unsigned*)x,
                                                 (const unsigned*)h, bias,
                                                 gamma, beta, d_out, N, E, C,
                                                 r1, r2);
  if (N > r2)
    k_agg<<<(N - r2 + 3) / 4, 256, 0, stream>>>(offs, bbase, slots,
                                                (const unsigned*)x,
                                                (const unsigned*)h, bias,
                                                gamma, beta, d_out, N, E, C,
                                                r2, N);
}

// Round 12
// 242.430 us; speedup vs baseline: 1.0537x; 1.0537x over previous
//
#include <hip/hip_runtime.h>
#include <hip/hip_bf16.h>

#define HIDC 64
#define NEG_SLOPE 0.2f
#define SCAN_G 128     // blocks in the two-phase scan

typedef __hip_bfloat16 bf16;
typedef short bf16x8 __attribute__((ext_vector_type(8)));
typedef float floatx4 __attribute__((ext_vector_type(4)));
typedef int intx4 __attribute__((ext_vector_type(4)));

static __device__ __forceinline__ float b2f(bf16 v) { return __bfloat162float(v); }

static __device__ __forceinline__ unsigned short f2us(float f) {
  bf16 b = __float2bfloat16(f);
  union { bf16 b; unsigned short u; } c;
  c.b = b;
  return c.u;
}

// dtype-specialized loads
template <bool FF>
static __device__ __forceinline__ float ld(const void* __restrict__ p, size_t i) {
  return FF ? ((const float*)p)[i] : b2f(((const bf16*)p)[i]);
}
static __device__ __forceinline__ float ldr(const void* __restrict__ p, size_t i,
                                            bool ff) {
  return ff ? ((const float*)p)[i] : b2f(((const bf16*)p)[i]);
}
template <bool I64>
static __device__ __forceinline__ int ldi(const int* __restrict__ p, long long i) {
  return I64 ? (int)((const long long*)p)[i] : p[i];
}
static __device__ __forceinline__ int clampN(int v, int N) {
  return ((unsigned)v < (unsigned)N) ? v : 0;
}

// nontemporal 16B load (slots are read exactly once in k_agg)
static __device__ __forceinline__ int4 ntload4(const int4* __restrict__ p) {
  intx4 v = __builtin_nontemporal_load((const intx4*)p);
  return make_int4(v.x, v.y, v.z, v.w);
}

// Per-wave local dtype detection (1 load + ballot; uniform across waves since
// every wave samples the same 32 words).
static __device__ __forceinline__ bool det_f32(const unsigned* __restrict__ hw) {
  unsigned w = hw[threadIdx.x & 31];
  int ex = (w >> 7) & 0xFF;
  unsigned long long b = __ballot(ex >= 99 && ex <= 135);
  return __popcll(b) < 32;  // true => fp32 inputs
}
static __device__ __forceinline__ bool det_i64(const int* __restrict__ ei) {
  int v = ei[2 * (threadIdx.x & 31) + 1];
  return __ballot(v != 0) == 0ULL;  // true => int64 layout
}

// --------- one-time W pre-swizzle: global W -> bf16 swizzled wg (32 KB) ------
// Round 12: k_xh's per-block W staging was a 64-deep scalar 2B load chain per
// thread into a 32KB LDS tile; the 40KB LDS/block also capped residency at 2
// blocks/CU (round-11 counters: occupancy 24%, VALU 7% -> latency-bound).
// W^T is read-only and reused by all 782 blocks, so swizzle it ONCE into
// global wg with the byte-exact layout the LDS tile had; k_xh's B-fragment
// reads (L2-hot, 32KB) use identical indexing with wls->wg.
__global__ void __launch_bounds__(256) k_wswz(
    const void* __restrict__ W, const unsigned* __restrict__ hw,
    unsigned short* __restrict__ wg) {
  bool ff = det_f32(hw);
  int k = blockIdx.x;        // 0..63  (K index)
  int c = threadIdx.x;       // 0..255 (global col)
  unsigned short v = ff ? f2us(((const float*)W)[(size_t)k * 256 + c])
                        : ((const unsigned short*)W)[(size_t)k * 256 + c];
  int jn = c & 63, hd = c >> 6;
  int r = hd * 64 + (jn & 3) * 16 + (jn >> 2);   // column permutation
  int q = k >> 3, j = k & 7;
  wg[(size_t)r * 64 + (q ^ (r & 7)) * 8 + j] = v;
}

// ---------------- MFMA x-GEMM + logits + in-degree histogram ----------------
// Block = 64 nodes x 256 cols. h-tile (8 KB) staged in LDS (16B chunks of 8
// k-elems, chunk q XOR-swizzled by (row&7)); W fragments read DIRECTLY from
// the pre-swizzled global wg (no wls, no W staging chain). LDS = 8 KB/block.
// COLUMN PERMUTATION: within each head's 64 cols, global col j sits at wg row
// (j&3)*16 + (j>>2); each lane's 4 outputs are CONTIGUOUS -> ushort4 x stores.
// HISTOGRAM WITH RANK: capture atomicAdd's return into erank[e] (coalesced
// 4B); cnt padded to 1 counter/64B line (round-10, 800K atomics on 3.2K lines
// serialized).
template <bool FF, bool I64>
static __device__ __forceinline__ void xh_body(
    const void* __restrict__ h, const unsigned short* __restrict__ wg,
    const void* __restrict__ att_src, const void* __restrict__ att_dst,
    const int* __restrict__ ei, bf16* __restrict__ x,
    float* __restrict__ a_src, float* __restrict__ a_dst,
    int* __restrict__ cnt, int* __restrict__ erank, int N, int E,
    unsigned short* __restrict__ hls) {
  // histogram + rank capture (grid-stride; padded counters, 1 per 64B line)
  for (long long e = (long long)blockIdx.x * 256 + threadIdx.x; e < E;
       e += (long long)gridDim.x * 256) {
    int dst = clampN(ldi<I64>(ei, (long long)E + e), N);
    erank[e] = atomicAdd(&cnt[(size_t)dst * 16], 1);
  }
  const int t = threadIdx.x;
  const long long n0 = (long long)blockIdx.x * 64;
  {  // stage h tile: 64 rows x 8 chunks; thread -> (row=t>>2, 2 chunks)
    const int row = t >> 2;
    const long long n = n0 + row;
#pragma unroll
    for (int dq = 0; dq < 2; dq++) {
      int q = (t & 3) * 2 + dq;
      int4 v;
      if (n < N) {
        if (FF) {
          const float4* hp = (const float4*)h + n * 16 + q * 2;
          float4 f0 = hp[0], f1 = hp[1];
          v = make_int4((int)(f2us(f0.x) | ((unsigned)f2us(f0.y) << 16)),
                        (int)(f2us(f0.z) | ((unsigned)f2us(f0.w) << 16)),
                        (int)(f2us(f1.x) | ((unsigned)f2us(f1.y) << 16)),
                        (int)(f2us(f1.z) | ((unsigned)f2us(f1.w) << 16)));
        } else {
          v = *((const int4*)((const unsigned short*)h + n * 64 + q * 8));
        }
      } else {
        v = make_int4(0, 0, 0, 0);
      }
      *(int4*)&hls[row * 64 + (q ^ (row & 7)) * 8] = v;
    }
  }
  __syncthreads();
  const int w = t >> 6;          // wave = head = col group of 64
  const int lane = t & 63;
  const int lm = lane & 15, lq = lane >> 4;
  // B fragments straight from L2-hot wg (8 x 16B loads, all independent)
  bf16x8 bfrag[4][2];
#pragma unroll
  for (int ct = 0; ct < 4; ct++) {
    int c = w * 64 + ct * 16 + lm;   // wg row (global col w*64 + 4*lm + ct)
    bfrag[ct][0] = *(const bf16x8*)&wg[(size_t)c * 64 + ((lq) ^ (c & 7)) * 8];
    bfrag[ct][1] = *(const bf16x8*)&wg[(size_t)c * 64 + ((4 + lq) ^ (c & 7)) * 8];
  }
  bf16x8 af[4][2];
#pragma unroll
  for (int nt = 0; nt < 4; nt++)
#pragma unroll
    for (int ks = 0; ks < 2; ks++) {
      int m = nt * 16 + lm;
      int q = ks * 4 + lq;
      af[nt][ks] = *(const bf16x8*)&hls[m * 64 + (q ^ (m & 7)) * 8];
    }
  floatx4 acc[4][4];
#pragma unroll
  for (int nt = 0; nt < 4; nt++)
#pragma unroll
    for (int ct = 0; ct < 4; ct++) acc[nt][ct] = (floatx4){0.f, 0.f, 0.f, 0.f};
#pragma unroll
  for (int ct = 0; ct < 4; ct++) {
#pragma unroll
    for (int nt = 0; nt < 4; nt++) {
      acc[nt][ct] = __builtin_amdgcn_mfma_f32_16x16x32_bf16(af[nt][0],
                                                            bfrag[ct][0],
                                                            acc[nt][ct], 0, 0, 0);
      acc[nt][ct] = __builtin_amdgcn_mfma_f32_16x16x32_bf16(af[nt][1],
                                                            bfrag[ct][1],
                                                            acc[nt][ct], 0, 0, 0);
    }
  }
  // epilogue: vectorized x store + per-head logits via 16-lane shfl_xor
  float as_c[4], ad_c[4];
#pragma unroll
  for (int ct = 0; ct < 4; ct++) {
    as_c[ct] = ld<FF>(att_src, w * 64 + lm * 4 + ct);
    ad_c[ct] = ld<FF>(att_dst, w * 64 + lm * 4 + ct);
  }
#pragma unroll
  for (int nt = 0; nt < 4; nt++) {
    float ps[4] = {0.f, 0.f, 0.f, 0.f}, pd[4] = {0.f, 0.f, 0.f, 0.f};
#pragma unroll
    for (int ct = 0; ct < 4; ct++) {
#pragma unroll
      for (int r = 0; r < 4; r++) {
        ps[r] += acc[nt][ct][r] * as_c[ct];
        pd[r] += acc[nt][ct][r] * ad_c[ct];
      }
    }
    long long nb = n0 + nt * 16 + lq * 4;
#pragma unroll
    for (int r = 0; r < 4; r++) {
      long long n = nb + r;
      if (n < N) {
        ushort4 us = make_ushort4(f2us(acc[nt][0][r]), f2us(acc[nt][1][r]),
                                  f2us(acc[nt][2][r]), f2us(acc[nt][3][r]));
        *(ushort4*)&x[n * 256 + w * 64 + lm * 4] = us;
      }
    }
#pragma unroll
    for (int mask = 1; mask < 16; mask <<= 1) {
#pragma unroll
      for (int r = 0; r < 4; r++) {
        ps[r] += __shfl_xor(ps[r], mask);
        pd[r] += __shfl_xor(pd[r], mask);
      }
    }
    if (lm == 0) {
#pragma unroll
      for (int r = 0; r < 4; r++) {
        long long n = nb + r;
        if (n < N) {
          a_src[n * 4 + w] = ps[r];
          a_dst[n * 4 + w] = pd[r];
        }
      }
    }
  }
}

__global__ void __launch_bounds__(256) k_xh(
    const void* __restrict__ h, const unsigned short* __restrict__ wg,
    const void* __restrict__ att_src, const void* __restrict__ att_dst,
    const int* __restrict__ ei, bf16* __restrict__ x,
    float* __restrict__ a_src, float* __restrict__ a_dst,
    int* __restrict__ cnt, int* __restrict__ erank, int N, int E) {
  __shared__ alignas(16) unsigned short hls[64 * 64];    // 8 KB only
  bool f32 = det_f32((const unsigned*)h);
  bool i64 = det_i64(ei);
  if (f32) {
    if (i64) xh_body<true, true>(h, wg, att_src, att_dst, ei, x, a_src, a_dst, cnt, erank, N, E, hls);
    else     xh_body<true, false>(h, wg, att_src, att_dst, ei, x, a_src, a_dst, cnt, erank, N, E, hls);
  } else {
    if (i64) xh_body<false, true>(h, wg, att_src, att_dst, ei, x, a_src, a_dst, cnt, erank, N, E, hls);
    else     xh_body<false, false>(h, wg, att_src, att_dst, ei, x, a_src, a_dst, cnt, erank, N, E, hls);
  }
}

// ------------- scan: per-chunk local prefix + last-block bsum scan ----------
// Reads the PADDED cnt (one counter per 64B line) with plain loads — coherent
// across the kernel boundary. offs[] keeps the CHUNK-LOCAL exclusive prefix,
// bbase[] the per-chunk base; consumers add bbase[n / C].
__global__ void __launch_bounds__(1024) k_bscan(
    const void* __restrict__ W_edge, const void* __restrict__ att_edge,
    const unsigned* __restrict__ hw, const int* __restrict__ cnt,
    int* __restrict__ offs, int* __restrict__ bsum, int* __restrict__ bbase,
    int* __restrict__ done, float* __restrict__ M, int N) {
  int b = blockIdx.x, t = threadIdx.x;
  if (b == 0 && t < 768) {
    bool ff = det_f32(hw);
    int wv = t >> 6, lane = t & 63;
    int d = wv >> 2, hh = wv & 3;
    float p = ldr(W_edge, (size_t)d * 256 + hh * 64 + lane, ff) *
              ldr(att_edge, (size_t)hh * 64 + lane, ff);
#pragma unroll
    for (int o = 32; o; o >>= 1) p += __shfl_down(p, o);
    if (lane == 0) M[d * 4 + hh] = p;
  }
  const int C = (N + SCAN_G - 1) / SCAN_G;
  const int b0 = b * C;
  __shared__ int ts[1024];
  __shared__ int lastf;
  int v = 0;
  if (t < C && b0 + t < N) v = cnt[(size_t)(b0 + t) * 16];
  ts[t] = v;
  __syncthreads();
  for (int off = 1; off < 1024; off <<= 1) {
    int u = (t >= off) ? ts[t - off] : 0;
    __syncthreads();
    ts[t] += u;
    __syncthreads();
  }
  if (t < C && b0 + t < N) offs[b0 + t] = ts[t] - v;  // chunk-local exclusive
  if (t == 1023) {
    atomicExch(&bsum[b], ts[1023]);   // device-scope visible chunk total
    __threadfence();
    int old = atomicAdd(done, 1);
    lastf = (old == SCAN_G - 1) ? 1 : 0;
  }
  __syncthreads();
  if (lastf) {  // this block saw all other totals published
    int w = (t < SCAN_G) ? atomicAdd(&bsum[t], 0) : 0;  // atomic read
    ts[t] = w;
    __syncthreads();
    for (int off = 1; off < 1024; off <<= 1) {
      int u = (t >= off) ? ts[t - off] : 0;
      __syncthreads();
      ts[t] += u;
      __syncthreads();
    }
    if (t < SCAN_G) bbase[t] = ts[t] - w;  // exclusive block base
  }
}

// ---------------- fused edge weights + CSR scatter (one 16B slot) ------------
// Atomic-free: pos = offs_local[dst] + bbase[dst/C] + erank[e]. Slot store is
// a PLAIN int4 (through L2; ntstore quadrupled WRITE_SIZE, round-6 counters).
template <bool FF, bool I64>
static __device__ __forceinline__ void es_body(
    const int* __restrict__ ei, const void* __restrict__ eattr,
    const float* __restrict__ a_src, const float* __restrict__ a_dst,
    const float* __restrict__ M, const int* __restrict__ offs,
    const int* __restrict__ bbase, const int* __restrict__ erank,
    int4* __restrict__ slots, int E, int N, int C,
    unsigned* __restrict__ sattr) {
  const long long e0 = (long long)blockIdx.x * 256;
  {  // stage this block's eattr strip: 6B/edge (bf16) or 12B/edge (f32)
    const unsigned bpe = FF ? 12u : 6u;
    const unsigned* gsrc = (const unsigned*)((const char*)eattr + e0 * bpe);
    unsigned ndw = FF ? 768u : 384u;
    long long bytes_left = ((long long)E - e0) * bpe;
    if (bytes_left < 0) bytes_left = 0;
    unsigned max_dw = (unsigned)((bytes_left + 3) >> 2);
    if (ndw > max_dw) ndw = max_dw;
    for (unsigned i = threadIdx.x; i < ndw; i += 256) sattr[i] = gsrc[i];
  }
  __syncthreads();
  long long e = e0 + threadIdx.x;
  if (e >= E) return;
  int src = clampN(ldi<I64>(ei, e), N);
  int dst = clampN(ldi<I64>(ei, (long long)E + e), N);
  int pos = offs[dst] + bbase[dst / C] + erank[e];
  float ea0, ea1, ea2;
  if (FF) {
    const float* sf = (const float*)sattr;
    ea0 = sf[threadIdx.x * 3 + 0];
    ea1 = sf[threadIdx.x * 3 + 1];
    ea2 = sf[threadIdx.x * 3 + 2];
  } else {
    const unsigned short* su = (const unsigned short*)sattr;
    ea0 = __uint_as_float((unsigned)su[threadIdx.x * 3 + 0] << 16);
    ea1 = __uint_as_float((unsigned)su[threadIdx.x * 3 + 1] << 16);
    ea2 = __uint_as_float((unsigned)su[threadIdx.x * 3 + 2] << 16);
  }
  const float4 m0 = ((const float4*)M)[0];
  const float4 m1 = ((const float4*)M)[1];
  const float4 m2 = ((const float4*)M)[2];
  const float4 as4 = ((const float4*)a_src)[src];
  const float4 ad4 = ((const float4*)a_dst)[dst];
  float al[4];
  al[0] = as4.x + ad4.x + ea0 * m0.x + ea1 * m1.x + ea2 * m2.x;
  al[1] = as4.y + ad4.y + ea0 * m0.y + ea1 * m1.y + ea2 * m2.y;
  al[2] = as4.z + ad4.z + ea0 * m0.z + ea1 * m1.z + ea2 * m2.z;
  al[3] = as4.w + ad4.w + ea0 * m0.w + ea1 * m1.w + ea2 * m2.w;
  unsigned short u[4];
#pragma unroll
  for (int hh = 0; hh < 4; hh++) {
    float a = al[hh];
    a = (a > 0.f) ? a : NEG_SLOPE * a;
    a = fminf(fmaxf(a, -60.f), 60.f);
    u[hh] = f2us(__expf(a));
  }
  slots[pos] = make_int4(src, (int)(u[0] | ((unsigned)u[1] << 16)),
                         (int)(u[2] | ((unsigned)u[3] << 16)), 0);
}

__global__ void __launch_bounds__(256) k_es(
    const int* __restrict__ ei, const void* __restrict__ eattr,
    const float* __restrict__ a_src, const float* __restrict__ a_dst,
    const float* __restrict__ M, const unsigned* __restrict__ hw,
    const int* __restrict__ offs, const int* __restrict__ bbase,
    const int* __restrict__ erank, int4* __restrict__ slots, int E, int N,
    int C) {
  __shared__ unsigned sattr[768];
  bool f32 = det_f32(hw);
  bool i64 = det_i64(ei);
  if (f32) {
    if (i64) es_body<true, true>(ei, eattr, a_src, a_dst, M, offs, bbase, erank, slots, E, N, C, sattr);
    else     es_body<true, false>(ei, eattr, a_src, a_dst, M, offs, bbase, erank, slots, E, N, C, sattr);
  } else {
    if (i64) es_body<false, true>(ei, eattr, a_src, a_dst, M, offs, bbase, erank, slots, E, N, C, sattr);
    else     es_body<false, false>(ei, eattr, a_src, a_dst, M, offs, bbase, erank, slots, E, N, C, sattr);
  }
}

// ---------------- aggregation + head-mean + LayerNorm + SiLU -----------------
// Round-3 winner (one wave/node, uint2/lane, scalar slot base via
// readfirstlane, 8-deep MLP, nt slot loads), single full-range dispatch
// (round-11's 3-way split cost ~15us in drain tails — reverted).
static __device__ __forceinline__ uint2 xgat(const uint2* __restrict__ xr,
                                             int src, int lane) {
  int ss = __builtin_amdgcn_readfirstlane(src);
  return xr[(size_t)(unsigned)ss * 64 + lane];
}

__global__ void __launch_bounds__(256) k_agg(
    const int* __restrict__ offs, const int* __restrict__ bbase,
    const int4* __restrict__ slots, const unsigned* __restrict__ xu,
    const unsigned* __restrict__ hw, const void* __restrict__ bias,
    const void* __restrict__ gamma, const void* __restrict__ beta,
    void* __restrict__ out, int N, int E, int C) {
  const int t = threadIdx.x;
  const int wv = t >> 6, lane = t & 63;
  const int n = blockIdx.x * 4 + wv;
  if (n >= N) return;
  const int head2 = lane >> 5;                       // which packed word (q.y/q.z)
  const unsigned wshift = (lane & 16) ? 0u : 16u;    // even head -> lo16
  const uint2* __restrict__ xr = (const uint2*)xu;   // [N][64] uint2 rows

  int s0 = __builtin_amdgcn_readfirstlane(offs[n] + bbase[n / C]);
  int s1 = (n + 1 < N)
               ? __builtin_amdgcn_readfirstlane(offs[n + 1] + bbase[(n + 1) / C])
               : E;

  float a0 = 0.f, a1 = 0.f, a2 = 0.f, a3 = 0.f, ws = 0.f;

#define ACC4(q, d)                                                    \
  do {                                                                \
    unsigned ee = head2 ? (unsigned)(q).z : (unsigned)(q).y;          \
    float wv_ = __uint_as_float((ee << wshift) & 0xffff0000u);        \
    a0 += wv_ * __uint_as_float((d).x << 16);                         \
    a1 += wv_ * __uint_as_float((d).x & 0xffff0000u);                 \
    a2 += wv_ * __uint_as_float((d).y << 16);                         \
    a3 += wv_ * __uint_as_float((d).y & 0xffff0000u);                 \
    ws += wv_;                                                        \
  } while (0)

  int i = s0;
  for (; i + 8 <= s1; i += 8) {   // 8 slot loads, then 8 gathers in flight
    int4 q0 = ntload4(&slots[i + 0]);
    int4 q1 = ntload4(&slots[i + 1]);
    int4 q2 = ntload4(&slots[i + 2]);
    int4 q3 = ntload4(&slots[i + 3]);
    int4 q4 = ntload4(&slots[i + 4]);
    int4 q5 = ntload4(&slots[i + 5]);
    int4 q6 = ntload4(&slots[i + 6]);
    int4 q7 = ntload4(&slots[i + 7]);
    uint2 d0 = xgat(xr, q0.x, lane);
    uint2 d1 = xgat(xr, q1.x, lane);
    uint2 d2 = xgat(xr, q2.x, lane);
    uint2 d3 = xgat(xr, q3.x, lane);
    uint2 d4 = xgat(xr, q4.x, lane);
    uint2 d5 = xgat(xr, q5.x, lane);
    uint2 d6 = xgat(xr, q6.x, lane);
    uint2 d7 = xgat(xr, q7.x, lane);
    ACC4(q0, d0); ACC4(q1, d1); ACC4(q2, d2); ACC4(q3, d3);
    ACC4(q4, d4); ACC4(q5, d5); ACC4(q6, d6); ACC4(q7, d7);
  }
  for (; i + 4 <= s1; i += 4) {
    int4 q0 = ntload4(&slots[i + 0]);
    int4 q1 = ntload4(&slots[i + 1]);
    int4 q2 = ntload4(&slots[i + 2]);
    int4 q3 = ntload4(&slots[i + 3]);
    uint2 d0 = xgat(xr, q0.x, lane);
    uint2 d1 = xgat(xr, q1.x, lane);
    uint2 d2 = xgat(xr, q2.x, lane);
    uint2 d3 = xgat(xr, q3.x, lane);
    ACC4(q0, d0); ACC4(q1, d1); ACC4(q2, d2); ACC4(q3, d3);
  }
  for (; i < s1; i++) {
    int4 q = ntload4(&slots[i]);
    uint2 d = xgat(xr, q.x, lane);
    ACC4(q, d);
  }
#undef ACC4

  // per-head softmax normalization, then mean over the 4 heads (xor 16,32)
  float inv = 1.f / (ws + 1e-16f);
  float v0 = a0 * inv, v1 = a1 * inv, v2 = a2 * inv, v3 = a3 * inv;
  v0 += __shfl_xor(v0, 16); v1 += __shfl_xor(v1, 16);
  v2 += __shfl_xor(v2, 16); v3 += __shfl_xor(v3, 16);
  v0 += __shfl_xor(v0, 32); v1 += __shfl_xor(v1, 32);
  v2 += __shfl_xor(v2, 32); v3 += __shfl_xor(v3, 32);

  bool ff = det_f32(hw);
  const int c0 = (lane & 15) * 4;
  float m0 = v0 * 0.25f + ldr(bias, c0 + 0, ff);
  float m1 = v1 * 0.25f + ldr(bias, c0 + 1, ff);
  float m2 = v2 * 0.25f + ldr(bias, c0 + 2, ff);
  float m3 = v3 * 0.25f + ldr(bias, c0 + 3, ff);

  // LayerNorm over 64 channels: reduce within the 16-lane quad group
  float s = (m0 + m1) + (m2 + m3);
  s += __shfl_xor(s, 1); s += __shfl_xor(s, 2);
  s += __shfl_xor(s, 4); s += __shfl_xor(s, 8);
  float mu = s * 0.015625f;
  float d0 = m0 - mu, d1 = m1 - mu, d2 = m2 - mu, d3 = m3 - mu;
  float vq = (d0 * d0 + d1 * d1) + (d2 * d2 + d3 * d3);
  vq += __shfl_xor(vq, 1); vq += __shfl_xor(vq, 2);
  vq += __shfl_xor(vq, 4); vq += __shfl_xor(vq, 8);
  float rstd = rsqrtf(vq * 0.015625f + 1e-5f);

  if ((lane >> 4) == 0) {  // one 16-lane group writes the node's 64 channels
    float y0 = d0 * rstd * ldr(gamma, c0 + 0, ff) + ldr(beta, c0 + 0, ff);
    float y1 = d1 * rstd * ldr(gamma, c0 + 1, ff) + ldr(beta, c0 + 1, ff);
    float y2 = d2 * rstd * ldr(gamma, c0 + 2, ff) + ldr(beta, c0 + 2, ff);
    float y3 = d3 * rstd * ldr(gamma, c0 + 3, ff) + ldr(beta, c0 + 3, ff);
    float r0 = y0 / (1.f + __expf(-y0));
    float r1 = y1 / (1.f + __expf(-y1));
    float r2 = y2 / (1.f + __expf(-y2));
    float r3 = y3 / (1.f + __expf(-y3));
    size_t ob = (size_t)n * 64 + c0;
    if (ff) {
      *(float4*)((float*)out + ob) = make_float4(r0, r1, r2, r3);
    } else {
      *(ushort4*)((bf16*)out + ob) =
          make_ushort4(f2us(r0), f2us(r1), f2us(r2), f2us(r3));
    }
  }
}

extern "C" void kernel_launch(void* const* d_in, const int* in_sizes, int n_in,
                              void* d_out, int out_size, void* d_ws,
                              size_t ws_size, hipStream_t stream) {
  const void* h        = d_in[1];
  const int*  ei       = (const int*)d_in[2];
  const void* eattr    = d_in[3];
  const void* W        = d_in[4];
  const void* att_src  = d_in[5];
  const void* att_dst  = d_in[6];
  const void* W_edge   = d_in[7];
  const void* att_edge = d_in[8];
  const void* bias     = d_in[9];
  const void* gamma    = d_in[10];
  const void* beta     = d_in[11];

  const int N = in_sizes[1] / HIDC;       // h has N*64 elements (any dtype)
  const int E = in_sizes[3] / 3;          // edge_attr has E*3 elements
  const int C = (N + SCAN_G - 1) / SCAN_G;

  // Workspace layout (~47 MB), 16B-aligned segments.
  char* p = (char*)d_ws;
  float* M    = (float*)p; p += 64;                      // 12 floats
  bf16* x     = (bf16*)p;  p += (size_t)N * 256 * 2;     // 25.6 MB
  float* asrc = (float*)p; p += (size_t)N * 4 * 4;       // 0.8 MB
  float* adst = (float*)p; p += (size_t)N * 4 * 4;       // 0.8 MB
  int4* slots = (int4*)p;  p += (size_t)E * 16;          // 12.8 MB
  int* cnt    = (int*)p;   p += (size_t)N * 64;          // 3.2 MB, 1 ctr/64B line
  int* done   = (int*)p;   p += 64;                      // zeroed (with cnt)
  int* offs   = (int*)p;   p += ((size_t)N + 4) * 4;
  int* erank  = (int*)p;   p += (size_t)E * 4;           // 3.2 MB
  int* bsum   = (int*)p;   p += SCAN_G * 4;
  int* bbase  = (int*)p;   p += SCAN_G * 4;
  unsigned short* wg = (unsigned short*)p; p += 64 * 256 * 2;  // 32 KB

  size_t need = (size_t)(p - (char*)d_ws);
  if (ws_size < need || N <= 0 || E <= 0) {
    hipMemsetAsync(d_out, 0, (size_t)out_size * 2, stream);
    return;
  }

  hipMemsetAsync(cnt, 0, (size_t)N * 64 + 64, stream);  // cnt + done

  k_wswz<<<64, 256, 0, stream>>>(W, (const unsigned*)h, wg);
  k_xh<<<(N + 63) / 64, 256, 0, stream>>>(h, wg, att_src, att_dst, ei, x,
                                          asrc, adst, cnt, erank, N, E);
  k_bscan<<<SCAN_G, 1024, 0, stream>>>(W_edge, att_edge, (const unsigned*)h,
                                       cnt, offs, bsum, bbase, done, M, N);
  k_es<<<(E + 255) / 256, 256, 0, stream>>>(ei, eattr, asrc, adst, M,
                                            (const unsigned*)h, offs, bbase,
                                            erank, slots, E, N, C);
  k_agg<<<(N + 3) / 4, 256, 0, stream>>>(offs, bbase, slots, (const unsigned*)x,
                                         (const unsigned*)h, bias, gamma, beta,
                                         d_out, N, E, C);
}

// Round 13
// 237.011 us; speedup vs baseline: 1.0778x; 1.0229x over previous
//
#include <hip/hip_runtime.h>
#include <hip/hip_bf16.h>

#define HIDC 64
#define NEG_SLOPE 0.2f
#define SCAN_G 128     // blocks in the two-phase scan

typedef __hip_bfloat16 bf16;
typedef short bf16x8 __attribute__((ext_vector_type(8)));
typedef float floatx4 __attribute__((ext_vector_type(4)));

static __device__ __forceinline__ float b2f(bf16 v) { return __bfloat162float(v); }

static __device__ __forceinline__ unsigned short f2us(float f) {
  bf16 b = __float2bfloat16(f);
  union { bf16 b; unsigned short u; } c;
  c.b = b;
  return c.u;
}

// dtype-specialized loads
template <bool FF>
static __device__ __forceinline__ float ld(const void* __restrict__ p, size_t i) {
  return FF ? ((const float*)p)[i] : b2f(((const bf16*)p)[i]);
}
static __device__ __forceinline__ float ldr(const void* __restrict__ p, size_t i,
                                            bool ff) {
  return ff ? ((const float*)p)[i] : b2f(((const bf16*)p)[i]);
}
template <bool I64>
static __device__ __forceinline__ int ldi(const int* __restrict__ p, long long i) {
  return I64 ? (int)((const long long*)p)[i] : p[i];
}
static __device__ __forceinline__ int clampN(int v, int N) {
  return ((unsigned)v < (unsigned)N) ? v : 0;
}

// Per-wave local dtype detection (1 load + ballot; uniform across waves since
// every wave samples the same 32 words).
static __device__ __forceinline__ bool det_f32(const unsigned* __restrict__ hw) {
  unsigned w = hw[threadIdx.x & 31];
  int ex = (w >> 7) & 0xFF;
  unsigned long long b = __ballot(ex >= 99 && ex <= 135);
  return __popcll(b) < 32;  // true => fp32 inputs
}
static __device__ __forceinline__ bool det_i64(const int* __restrict__ ei) {
  int v = ei[2 * (threadIdx.x & 31) + 1];
  return __ballot(v != 0) == 0ULL;  // true => int64 layout
}

// ---------------- MFMA x-GEMM + logits + in-degree histogram ----------------
// Round 13 = round-10 pipeline (239.9us verified best; round-12's W
// pre-swizzle was null and is reverted) + histogram UNROLLED BY 4: the
// grid-stride loop's erank[e]=atomicAdd(...) was a per-thread serial chain
// (load -> wait -> atomic-with-return -> wait -> store, ~4 sequential
// round-trips); batching 4 independent loads, then 4 atomics, then 4 stores
// keeps 4 round-trips in flight. cnt stays padded to 1 counter/64B line
// (round-10, +3.5us).
template <bool FF, bool I64>
static __device__ __forceinline__ void xh_body(
    const void* __restrict__ h, const void* __restrict__ W,
    const void* __restrict__ att_src, const void* __restrict__ att_dst,
    const int* __restrict__ ei, bf16* __restrict__ x,
    float* __restrict__ a_src, float* __restrict__ a_dst,
    int* __restrict__ cnt, int* __restrict__ erank, int N, int E,
    unsigned short* __restrict__ hls, unsigned short* __restrict__ wls) {
  // histogram + rank capture, 4 edges in flight per thread
  {
    const long long str = (long long)gridDim.x * 256;
    long long e = (long long)blockIdx.x * 256 + threadIdx.x;
    for (; e + 3 * str < E; e += 4 * str) {
      int dA = clampN(ldi<I64>(ei, (long long)E + e), N);
      int dB = clampN(ldi<I64>(ei, (long long)E + e + str), N);
      int dC = clampN(ldi<I64>(ei, (long long)E + e + 2 * str), N);
      int dD = clampN(ldi<I64>(ei, (long long)E + e + 3 * str), N);
      int rA = atomicAdd(&cnt[(size_t)dA * 16], 1);
      int rB = atomicAdd(&cnt[(size_t)dB * 16], 1);
      int rC = atomicAdd(&cnt[(size_t)dC * 16], 1);
      int rD = atomicAdd(&cnt[(size_t)dD * 16], 1);
      erank[e] = rA;
      erank[e + str] = rB;
      erank[e + 2 * str] = rC;
      erank[e + 3 * str] = rD;
    }
    for (; e < E; e += str) {
      int dst = clampN(ldi<I64>(ei, (long long)E + e), N);
      erank[e] = atomicAdd(&cnt[(size_t)dst * 16], 1);
    }
  }
  const int t = threadIdx.x;
  const long long n0 = (long long)blockIdx.x * 64;
  {  // stage W^T: thread t = global col c; LDS row permuted within head
    const int c = t;
    const int jn = c & 63, hd = c >> 6;
    const int r = hd * 64 + (jn & 3) * 16 + (jn >> 2);
#pragma unroll
    for (int q = 0; q < 8; q++) {
      unsigned short u[8];
#pragma unroll
      for (int j = 0; j < 8; j++) {
        int k = q * 8 + j;
        u[j] = FF ? f2us(((const float*)W)[(size_t)k * 256 + c])
                  : ((const unsigned short*)W)[(size_t)k * 256 + c];
      }
      int4 v = make_int4((int)(u[0] | ((unsigned)u[1] << 16)),
                         (int)(u[2] | ((unsigned)u[3] << 16)),
                         (int)(u[4] | ((unsigned)u[5] << 16)),
                         (int)(u[6] | ((unsigned)u[7] << 16)));
      *(int4*)&wls[r * 64 + (q ^ (r & 7)) * 8] = v;
    }
  }
  {  // stage h tile: 64 rows x 8 chunks; thread -> (row=t>>2, 2 chunks)
    const int row = t >> 2;
    const long long n = n0 + row;
#pragma unroll
    for (int dq = 0; dq < 2; dq++) {
      int q = (t & 3) * 2 + dq;
      int4 v;
      if (n < N) {
        if (FF) {
          const float4* hp = (const float4*)h + n * 16 + q * 2;
          float4 f0 = hp[0], f1 = hp[1];
          v = make_int4((int)(f2us(f0.x) | ((unsigned)f2us(f0.y) << 16)),
                        (int)(f2us(f0.z) | ((unsigned)f2us(f0.w) << 16)),
                        (int)(f2us(f1.x) | ((unsigned)f2us(f1.y) << 16)),
                        (int)(f2us(f1.z) | ((unsigned)f2us(f1.w) << 16)));
        } else {
          v = *((const int4*)((const unsigned short*)h + n * 64 + q * 8));
        }
      } else {
        v = make_int4(0, 0, 0, 0);
      }
      *(int4*)&hls[row * 64 + (q ^ (row & 7)) * 8] = v;
    }
  }
  __syncthreads();
  const int w = t >> 6;          // wave = head = col group of 64
  const int lane = t & 63;
  const int lm = lane & 15, lq = lane >> 4;
  bf16x8 af[4][2];
#pragma unroll
  for (int nt = 0; nt < 4; nt++)
#pragma unroll
    for (int ks = 0; ks < 2; ks++) {
      int m = nt * 16 + lm;
      int q = ks * 4 + lq;
      af[nt][ks] = *(const bf16x8*)&hls[m * 64 + (q ^ (m & 7)) * 8];
    }
  floatx4 acc[4][4];
#pragma unroll
  for (int nt = 0; nt < 4; nt++)
#pragma unroll
    for (int ct = 0; ct < 4; ct++) acc[nt][ct] = (floatx4){0.f, 0.f, 0.f, 0.f};
#pragma unroll
  for (int ct = 0; ct < 4; ct++) {
    int c = w * 64 + ct * 16 + lm;   // LDS row (global col w*64 + 4*lm + ct)
    bf16x8 b0 = *(const bf16x8*)&wls[c * 64 + ((lq) ^ (c & 7)) * 8];
    bf16x8 b1 = *(const bf16x8*)&wls[c * 64 + ((4 + lq) ^ (c & 7)) * 8];
#pragma unroll
    for (int nt = 0; nt < 4; nt++) {
      acc[nt][ct] = __builtin_amdgcn_mfma_f32_16x16x32_bf16(af[nt][0], b0,
                                                            acc[nt][ct], 0, 0, 0);
      acc[nt][ct] = __builtin_amdgcn_mfma_f32_16x16x32_bf16(af[nt][1], b1,
                                                            acc[nt][ct], 0, 0, 0);
    }
  }
  // epilogue: vectorized x store + per-head logits via 16-lane shfl_xor
  float as_c[4], ad_c[4];
#pragma unroll
  for (int ct = 0; ct < 4; ct++) {
    as_c[ct] = ld<FF>(att_src, w * 64 + lm * 4 + ct);
    ad_c[ct] = ld<FF>(att_dst, w * 64 + lm * 4 + ct);
  }
#pragma unroll
  for (int nt = 0; nt < 4; nt++) {
    float ps[4] = {0.f, 0.f, 0.f, 0.f}, pd[4] = {0.f, 0.f, 0.f, 0.f};
#pragma unroll
    for (int ct = 0; ct < 4; ct++) {
#pragma unroll
      for (int r = 0; r < 4; r++) {
        ps[r] += acc[nt][ct][r] * as_c[ct];
        pd[r] += acc[nt][ct][r] * ad_c[ct];
      }
    }
    long long nb = n0 + nt * 16 + lq * 4;
#pragma unroll
    for (int r = 0; r < 4; r++) {
      long long n = nb + r;
      if (n < N) {
        ushort4 us = make_ushort4(f2us(acc[nt][0][r]), f2us(acc[nt][1][r]),
                                  f2us(acc[nt][2][r]), f2us(acc[nt][3][r]));
        *(ushort4*)&x[n * 256 + w * 64 + lm * 4] = us;
      }
    }
#pragma unroll
    for (int mask = 1; mask < 16; mask <<= 1) {
#pragma unroll
      for (int r = 0; r < 4; r++) {
        ps[r] += __shfl_xor(ps[r], mask);
        pd[r] += __shfl_xor(pd[r], mask);
      }
    }
    if (lm == 0) {
#pragma unroll
      for (int r = 0; r < 4; r++) {
        long long n = nb + r;
        if (n < N) {
          a_src[n * 4 + w] = ps[r];
          a_dst[n * 4 + w] = pd[r];
        }
      }
    }
  }
}

__global__ void __launch_bounds__(256) k_xh(
    const void* __restrict__ h, const void* __restrict__ W,
    const void* __restrict__ att_src, const void* __restrict__ att_dst,
    const int* __restrict__ ei, bf16* __restrict__ x,
    float* __restrict__ a_src, float* __restrict__ a_dst,
    int* __restrict__ cnt, int* __restrict__ erank, int N, int E) {
  __shared__ alignas(16) unsigned short hls[64 * 64];    // 8 KB (shared by all
  __shared__ alignas(16) unsigned short wls[256 * 64];   // 32 KB  instantiations)
  bool f32 = det_f32((const unsigned*)h);
  bool i64 = det_i64(ei);
  if (f32) {
    if (i64) xh_body<true, true>(h, W, att_src, att_dst, ei, x, a_src, a_dst, cnt, erank, N, E, hls, wls);
    else     xh_body<true, false>(h, W, att_src, att_dst, ei, x, a_src, a_dst, cnt, erank, N, E, hls, wls);
  } else {
    if (i64) xh_body<false, true>(h, W, att_src, att_dst, ei, x, a_src, a_dst, cnt, erank, N, E, hls, wls);
    else     xh_body<false, false>(h, W, att_src, att_dst, ei, x, a_src, a_dst, cnt, erank, N, E, hls, wls);
  }
}

// ------------- scan: per-chunk local prefix + last-block bsum scan ----------
// Reads the PADDED cnt (one counter per 64B line) with plain loads — coherent
// across the kernel boundary. offs[] keeps the CHUNK-LOCAL exclusive prefix,
// bbase[] the per-chunk base; consumers add bbase[n / C].
__global__ void __launch_bounds__(1024) k_bscan(
    const void* __restrict__ W_edge, const void* __restrict__ att_edge,
    const unsigned* __restrict__ hw, const int* __restrict__ cnt,
    int* __restrict__ offs, int* __restrict__ bsum, int* __restrict__ bbase,
    int* __restrict__ done, float* __restrict__ M, int N) {
  int b = blockIdx.x, t = threadIdx.x;
  if (b == 0 && t < 768) {
    bool ff = det_f32(hw);
    int wv = t >> 6, lane = t & 63;
    int d = wv >> 2, hh = wv & 3;
    float p = ldr(W_edge, (size_t)d * 256 + hh * 64 + lane, ff) *
              ldr(att_edge, (size_t)hh * 64 + lane, ff);
#pragma unroll
    for (int o = 32; o; o >>= 1) p += __shfl_down(p, o);
    if (lane == 0) M[d * 4 + hh] = p;
  }
  const int C = (N + SCAN_G - 1) / SCAN_G;
  const int b0 = b * C;
  __shared__ int ts[1024];
  __shared__ int lastf;
  int v = 0;
  if (t < C && b0 + t < N) v = cnt[(size_t)(b0 + t) * 16];
  ts[t] = v;
  __syncthreads();
  for (int off = 1; off < 1024; off <<= 1) {
    int u = (t >= off) ? ts[t - off] : 0;
    __syncthreads();
    ts[t] += u;
    __syncthreads();
  }
  if (t < C && b0 + t < N) offs[b0 + t] = ts[t] - v;  // chunk-local exclusive
  if (t == 1023) {
    atomicExch(&bsum[b], ts[1023]);   // device-scope visible chunk total
    __threadfence();
    int old = atomicAdd(done, 1);
    lastf = (old == SCAN_G - 1) ? 1 : 0;
  }
  __syncthreads();
  if (lastf) {  // this block saw all other totals published
    int w = (t < SCAN_G) ? atomicAdd(&bsum[t], 0) : 0;  // atomic read
    ts[t] = w;
    __syncthreads();
    for (int off = 1; off < 1024; off <<= 1) {
      int u = (t >= off) ? ts[t - off] : 0;
      __syncthreads();
      ts[t] += u;
      __syncthreads();
    }
    if (t < SCAN_G) bbase[t] = ts[t] - w;  // exclusive block base
  }
}

// ---------------- fused edge weights + CSR scatter (one 16B slot) ------------
// Atomic-free: pos = offs_local[dst] + bbase[dst/C] + erank[e]. Slot store is
// a PLAIN int4 (through L2; ntstore quadrupled WRITE_SIZE, round-6 counters).
template <bool FF, bool I64>
static __device__ __forceinline__ void es_body(
    const int* __restrict__ ei, const void* __restrict__ eattr,
    const float* __restrict__ a_src, const float* __restrict__ a_dst,
    const float* __restrict__ M, const int* __restrict__ offs,
    const int* __restrict__ bbase, const int* __restrict__ erank,
    int4* __restrict__ slots, int E, int N, int C,
    unsigned* __restrict__ sattr) {
  const long long e0 = (long long)blockIdx.x * 256;
  {  // stage this block's eattr strip: 6B/edge (bf16) or 12B/edge (f32)
    const unsigned bpe = FF ? 12u : 6u;
    const unsigned* gsrc = (const unsigned*)((const char*)eattr + e0 * bpe);
    unsigned ndw = FF ? 768u : 384u;
    long long bytes_left = ((long long)E - e0) * bpe;
    if (bytes_left < 0) bytes_left = 0;
    unsigned max_dw = (unsigned)((bytes_left + 3) >> 2);
    if (ndw > max_dw) ndw = max_dw;
    for (unsigned i = threadIdx.x; i < ndw; i += 256) sattr[i] = gsrc[i];
  }
  __syncthreads();
  long long e = e0 + threadIdx.x;
  if (e >= E) return;
  int src = clampN(ldi<I64>(ei, e), N);
  int dst = clampN(ldi<I64>(ei, (long long)E + e), N);
  int pos = offs[dst] + bbase[dst / C] + erank[e];
  float ea0, ea1, ea2;
  if (FF) {
    const float* sf = (const float*)sattr;
    ea0 = sf[threadIdx.x * 3 + 0];
    ea1 = sf[threadIdx.x * 3 + 1];
    ea2 = sf[threadIdx.x * 3 + 2];
  } else {
    const unsigned short* su = (const unsigned short*)sattr;
    ea0 = __uint_as_float((unsigned)su[threadIdx.x * 3 + 0] << 16);
    ea1 = __uint_as_float((unsigned)su[threadIdx.x * 3 + 1] << 16);
    ea2 = __uint_as_float((unsigned)su[threadIdx.x * 3 + 2] << 16);
  }
  const float4 m0 = ((const float4*)M)[0];
  const float4 m1 = ((const float4*)M)[1];
  const float4 m2 = ((const float4*)M)[2];
  const float4 as4 = ((const float4*)a_src)[src];
  const float4 ad4 = ((const float4*)a_dst)[dst];
  float al[4];
  al[0] = as4.x + ad4.x + ea0 * m0.x + ea1 * m1.x + ea2 * m2.x;
  al[1] = as4.y + ad4.y + ea0 * m0.y + ea1 * m1.y + ea2 * m2.y;
  al[2] = as4.z + ad4.z + ea0 * m0.z + ea1 * m1.z + ea2 * m2.z;
  al[3] = as4.w + ad4.w + ea0 * m0.w + ea1 * m1.w + ea2 * m2.w;
  unsigned short u[4];
#pragma unroll
  for (int hh = 0; hh < 4; hh++) {
    float a = al[hh];
    a = (a > 0.f) ? a : NEG_SLOPE * a;
    a = fminf(fmaxf(a, -60.f), 60.f);
    u[hh] = f2us(__expf(a));
  }
  slots[pos] = make_int4(src, (int)(u[0] | ((unsigned)u[1] << 16)),
                         (int)(u[2] | ((unsigned)u[3] << 16)), 0);
}

__global__ void __launch_bounds__(256) k_es(
    const int* __restrict__ ei, const void* __restrict__ eattr,
    const float* __restrict__ a_src, const float* __restrict__ a_dst,
    const float* __restrict__ M, const unsigned* __restrict__ hw,
    const int* __restrict__ offs, const int* __restrict__ bbase,
    const int* __restrict__ erank, int4* __restrict__ slots, int E, int N,
    int C) {
  __shared__ unsigned sattr[768];
  bool f32 = det_f32(hw);
  bool i64 = det_i64(ei);
  if (f32) {
    if (i64) es_body<true, true>(ei, eattr, a_src, a_dst, M, offs, bbase, erank, slots, E, N, C, sattr);
    else     es_body<true, false>(ei, eattr, a_src, a_dst, M, offs, bbase, erank, slots, E, N, C, sattr);
  } else {
    if (i64) es_body<false, true>(ei, eattr, a_src, a_dst, M, offs, bbase, erank, slots, E, N, C, sattr);
    else     es_body<false, false>(ei, eattr, a_src, a_dst, M, offs, bbase, erank, slots, E, N, C, sattr);
  }
}

// ---------------- aggregation + head-mean + LayerNorm + SiLU -----------------
// Round-3 winner structure (one wave/node, uint2/lane, scalar slot base via
// readfirstlane, 8-deep MLP). Round 13: slot loads are PLAIN (not nt) —
// slots (12.8MB < 32MB aggregate L2) were just written through L2 by k_es;
// ntload bypassed L2 and re-fetched them from HBM. Watch k_agg FETCH_SIZE:
// ~12MB drop = slots L2-hit; flat = already evicted (revert next round).
static __device__ __forceinline__ uint2 xgat(const uint2* __restrict__ xr,
                                             int src, int lane) {
  int ss = __builtin_amdgcn_readfirstlane(src);
  return xr[(size_t)(unsigned)ss * 64 + lane];
}

__global__ void __launch_bounds__(256) k_agg(
    const int* __restrict__ offs, const int* __restrict__ bbase,
    const int4* __restrict__ slots, const unsigned* __restrict__ xu,
    const unsigned* __restrict__ hw, const void* __restrict__ bias,
    const void* __restrict__ gamma, const void* __restrict__ beta,
    void* __restrict__ out, int N, int E, int C) {
  const int t = threadIdx.x;
  const int wv = t >> 6, lane = t & 63;
  const int n = blockIdx.x * 4 + wv;
  if (n >= N) return;
  const int head2 = lane >> 5;                       // which packed word (q.y/q.z)
  const unsigned wshift = (lane & 16) ? 0u : 16u;    // even head -> lo16
  const uint2* __restrict__ xr = (const uint2*)xu;   // [N][64] uint2 rows

  int s0 = __builtin_amdgcn_readfirstlane(offs[n] + bbase[n / C]);
  int s1 = (n + 1 < N)
               ? __builtin_amdgcn_readfirstlane(offs[n + 1] + bbase[(n + 1) / C])
               : E;

  float a0 = 0.f, a1 = 0.f, a2 = 0.f, a3 = 0.f, ws = 0.f;

#define ACC4(q, d)                                                    \
  do {                                                                \
    unsigned ee = head2 ? (unsigned)(q).z : (unsigned)(q).y;          \
    float wv_ = __uint_as_float((ee << wshift) & 0xffff0000u);        \
    a0 += wv_ * __uint_as_float((d).x << 16);                         \
    a1 += wv_ * __uint_as_float((d).x & 0xffff0000u);                 \
    a2 += wv_ * __uint_as_float((d).y << 16);                         \
    a3 += wv_ * __uint_as_float((d).y & 0xffff0000u);                 \
    ws += wv_;                                                        \
  } while (0)

  int i = s0;
  for (; i + 8 <= s1; i += 8) {   // 8 slot loads, then 8 gathers in flight
    int4 q0 = slots[i + 0];
    int4 q1 = slots[i + 1];
    int4 q2 = slots[i + 2];
    int4 q3 = slots[i + 3];
    int4 q4 = slots[i + 4];
    int4 q5 = slots[i + 5];
    int4 q6 = slots[i + 6];
    int4 q7 = slots[i + 7];
    uint2 d0 = xgat(xr, q0.x, lane);
    uint2 d1 = xgat(xr, q1.x, lane);
    uint2 d2 = xgat(xr, q2.x, lane);
    uint2 d3 = xgat(xr, q3.x, lane);
    uint2 d4 = xgat(xr, q4.x, lane);
    uint2 d5 = xgat(xr, q5.x, lane);
    uint2 d6 = xgat(xr, q6.x, lane);
    uint2 d7 = xgat(xr, q7.x, lane);
    ACC4(q0, d0); ACC4(q1, d1); ACC4(q2, d2); ACC4(q3, d3);
    ACC4(q4, d4); ACC4(q5, d5); ACC4(q6, d6); ACC4(q7, d7);
  }
  for (; i + 4 <= s1; i += 4) {
    int4 q0 = slots[i + 0];
    int4 q1 = slots[i + 1];
    int4 q2 = slots[i + 2];
    int4 q3 = slots[i + 3];
    uint2 d0 = xgat(xr, q0.x, lane);
    uint2 d1 = xgat(xr, q1.x, lane);
    uint2 d2 = xgat(xr, q2.x, lane);
    uint2 d3 = xgat(xr, q3.x, lane);
    ACC4(q0, d0); ACC4(q1, d1); ACC4(q2, d2); ACC4(q3, d3);
  }
  for (; i < s1; i++) {
    int4 q = slots[i];
    uint2 d = xgat(xr, q.x, lane);
    ACC4(q, d);
  }
#undef ACC4

  // per-head softmax normalization, then mean over the 4 heads (xor 16,32)
  float inv = 1.f / (ws + 1e-16f);
  float v0 = a0 * inv, v1 = a1 * inv, v2 = a2 * inv, v3 = a3 * inv;
  v0 += __shfl_xor(v0, 16); v1 += __shfl_xor(v1, 16);
  v2 += __shfl_xor(v2, 16); v3 += __shfl_xor(v3, 16);
  v0 += __shfl_xor(v0, 32); v1 += __shfl_xor(v1, 32);
  v2 += __shfl_xor(v2, 32); v3 += __shfl_xor(v3, 32);

  bool ff = det_f32(hw);
  const int c0 = (lane & 15) * 4;
  float m0 = v0 * 0.25f + ldr(bias, c0 + 0, ff);
  float m1 = v1 * 0.25f + ldr(bias, c0 + 1, ff);
  float m2 = v2 * 0.25f + ldr(bias, c0 + 2, ff);
  float m3 = v3 * 0.25f + ldr(bias, c0 + 3, ff);

  // LayerNorm over 64 channels: reduce within the 16-lane quad group
  float s = (m0 + m1) + (m2 + m3);
  s += __shfl_xor(s, 1); s += __shfl_xor(s, 2);
  s += __shfl_xor(s, 4); s += __shfl_xor(s, 8);
  float mu = s * 0.015625f;
  float d0 = m0 - mu, d1 = m1 - mu, d2 = m2 - mu, d3 = m3 - mu;
  float vq = (d0 * d0 + d1 * d1) + (d2 * d2 + d3 * d3);
  vq += __shfl_xor(vq, 1); vq += __shfl_xor(vq, 2);
  vq += __shfl_xor(vq, 4); vq += __shfl_xor(vq, 8);
  float rstd = rsqrtf(vq * 0.015625f + 1e-5f);

  if ((lane >> 4) == 0) {  // one 16-lane group writes the node's 64 channels
    float y0 = d0 * rstd * ldr(gamma, c0 + 0, ff) + ldr(beta, c0 + 0, ff);
    float y1 = d1 * rstd * ldr(gamma, c0 + 1, ff) + ldr(beta, c0 + 1, ff);
    float y2 = d2 * rstd * ldr(gamma, c0 + 2, ff) + ldr(beta, c0 + 2, ff);
    float y3 = d3 * rstd * ldr(gamma, c0 + 3, ff) + ldr(beta, c0 + 3, ff);
    float r0 = y0 / (1.f + __expf(-y0));
    float r1 = y1 / (1.f + __expf(-y1));
    float r2 = y2 / (1.f + __expf(-y2));
    float r3 = y3 / (1.f + __expf(-y3));
    size_t ob = (size_t)n * 64 + c0;
    if (ff) {
      *(float4*)((float*)out + ob) = make_float4(r0, r1, r2, r3);
    } else {
      *(ushort4*)((bf16*)out + ob) =
          make_ushort4(f2us(r0), f2us(r1), f2us(r2), f2us(r3));
    }
  }
}

extern "C" void kernel_launch(void* const* d_in, const int* in_sizes, int n_in,
                              void* d_out, int out_size, void* d_ws,
                              size_t ws_size, hipStream_t stream) {
  const void* h        = d_in[1];
  const int*  ei       = (const int*)d_in[2];
  const void* eattr    = d_in[3];
  const void* W        = d_in[4];
  const void* att_src  = d_in[5];
  const void* att_dst  = d_in[6];
  const void* W_edge   = d_in[7];
  const void* att_edge = d_in[8];
  const void* bias     = d_in[9];
  const void* gamma    = d_in[10];
  const void* beta     = d_in[11];

  const int N = in_sizes[1] / HIDC;       // h has N*64 elements (any dtype)
  const int E = in_sizes[3] / 3;          // edge_attr has E*3 elements
  const int C = (N + SCAN_G - 1) / SCAN_G;

  // Workspace layout (~47 MB), 16B-aligned segments.
  char* p = (char*)d_ws;
  float* M    = (float*)p; p += 64;                      // 12 floats
  bf16* x     = (bf16*)p;  p += (size_t)N * 256 * 2;     // 25.6 MB
  float* asrc = (float*)p; p += (size_t)N * 4 * 4;       // 0.8 MB
  float* adst = (float*)p; p += (size_t)N * 4 * 4;       // 0.8 MB
  int4* slots = (int4*)p;  p += (size_t)E * 16;          // 12.8 MB
  int* cnt    = (int*)p;   p += (size_t)N * 64;          // 3.2 MB, 1 ctr/64B line
  int* done   = (int*)p;   p += 64;                      // zeroed (with cnt)
  int* offs   = (int*)p;   p += ((size_t)N + 4) * 4;
  int* erank  = (int*)p;   p += (size_t)E * 4;           // 3.2 MB
  int* bsum   = (int*)p;   p += SCAN_G * 4;
  int* bbase  = (int*)p;   p += SCAN_G * 4;

  size_t need = (size_t)(p - (char*)d_ws);
  if (ws_size < need || N <= 0 || E <= 0) {
    hipMemsetAsync(d_out, 0, (size_t)out_size * 2, stream);
    return;
  }

  hipMemsetAsync(cnt, 0, (size_t)N * 64 + 64, stream);  // cnt + done

  k_xh<<<(N + 63) / 64, 256, 0, stream>>>(h, W, att_src, att_dst, ei, x,
                                          asrc, adst, cnt, erank, N, E);
  k_bscan<<<SCAN_G, 1024, 0, stream>>>(W_edge, att_edge, (const unsigned*)h,
                                       cnt, offs, bsum, bbase, done, M, N);
  k_es<<<(E + 255) / 256, 256, 0, stream>>>(ei, eattr, asrc, adst, M,
                                            (const unsigned*)h, offs, bbase,
                                            erank, slots, E, N, C);
  k_agg<<<(N + 3) / 4, 256, 0, stream>>>(offs, bbase, slots, (const unsigned*)x,
                                         (const unsigned*)h, bias, gamma, beta,
                                         d_out, N, E, C);
}